// Round 6
// baseline (292.806 us; speedup 1.0000x reference)
//
#include <hip/hip_runtime.h>

#define T_TOKENS 4096
#define F_IN 4096
#define O_OUT 4096
#define SCALE_F 4.0f   // 16 / sqrt(16)

typedef __attribute__((ext_vector_type(8))) short bf16x8;
typedef __attribute__((ext_vector_type(4))) float f32x4;
typedef __attribute__((ext_vector_type(4))) int i32x4;

// ws layout (unsigned short elements)
#define WBM_E 0          // A packed:  [512 kb8][64 col][8]  = 262144
#define WRB_E 262144     // Wr packed: [512 kb8][16 col][8]  =  65536 (c0-3 hi, c4-7 lo, 8-15 zero)
#define BB_E  327680     // B packed:  [8 kb8][4096 o][8]    = 262144

__device__ __forceinline__ unsigned short f2bf(float f) {
    unsigned u = __float_as_uint(f);
    return (unsigned short)((u + 0x7fffu + ((u >> 16) & 1u)) >> 16);
}
__device__ __forceinline__ float bf2f(unsigned short h) {
    return __uint_as_float(((unsigned)h) << 16);
}
__device__ __forceinline__ int cvt_pk(float a, float b) {
    int r;
    asm("v_cvt_pk_bf16_f32 %0, %1, %2" : "=v"(r) : "v"(a), "v"(b));
    return r;   // low16 = bf16(a), high16 = bf16(b)
}

// ---------------------------------------------------------------------------
// kprep: pack A, Wr (hi/lo split), B into MFMA B-operand frags [k>>3][col][k&7].
// ---------------------------------------------------------------------------
__global__ __launch_bounds__(256) void kprep(const float* __restrict__ A,
                                             const float* __restrict__ Wr,
                                             const float* __restrict__ B,
                                             unsigned short* __restrict__ ws) {
    const int f = blockIdx.x * 256 + threadIdx.x;
    if (f < 32768) {                       // A frag: kb8 = f>>6, c = f&63
        const int kb8 = f >> 6, c = f & 63;
        const float* src = A + (size_t)c * F_IN + kb8 * 8;
        float4 a = *(const float4*)src, b = *(const float4*)(src + 4);
        i32x4 v;
        v[0] = cvt_pk(a.x, a.y); v[1] = cvt_pk(a.z, a.w);
        v[2] = cvt_pk(b.x, b.y); v[3] = cvt_pk(b.z, b.w);
        *(i32x4*)(ws + WBM_E + (size_t)f * 8) = v;
    } else if (f < 40960) {                // Wr frag (hi/lo, RNE split)
        const int j = f - 32768;
        const int kb8 = j >> 4, cc = j & 15;
        bf16x8 v = {0,0,0,0,0,0,0,0};
        if (cc < 8) {
            const float* src = Wr + (size_t)(cc & 3) * F_IN + kb8 * 8;
            float4 a = *(const float4*)src, b = *(const float4*)(src + 4);
            float ff[8] = {a.x, a.y, a.z, a.w, b.x, b.y, b.z, b.w};
            if (cc < 4) {
#pragma unroll
                for (int q = 0; q < 8; ++q) v[q] = (short)f2bf(ff[q]);
            } else {
#pragma unroll
                for (int q = 0; q < 8; ++q) {
                    unsigned short h = f2bf(ff[q]);
                    v[q] = (short)f2bf(ff[q] - bf2f(h));
                }
            }
        }
        *(bf16x8*)(ws + WRB_E + (size_t)j * 8) = v;
    } else if (f < 73728) {                // B frag: kb8 = j>>12, o = j&4095
        const int j = f - 40960;
        const int kb8 = j >> 12, o = j & 4095;
        const float* src = B + ((size_t)(kb8 >> 1) * O_OUT + o) * 16 + (kb8 & 1) * 8;
        float4 a = *(const float4*)src, b = *(const float4*)(src + 4);
        i32x4 v;
        v[0] = cvt_pk(a.x, a.y); v[1] = cvt_pk(a.z, a.w);
        v[2] = cvt_pk(b.x, b.y); v[3] = cvt_pk(b.z, b.w);
        *(i32x4*)(ws + BB_E + (size_t)j * 8) = v;
    }
}

// ---------------------------------------------------------------------------
// kfused: grid 256, 1024 thr (16 waves). Weights (K-chunk 256/wave) and B
// (col-chunk 256/wave) preloaded to registers ONCE. Then G=4 generations of
// 4 tokens: x-read MFMA -> LDS reduce (dbuf) -> gate -> pack -> B-MFMA +
// float4 stores. Stores(g) overlap x-loads(g+1) -> read/write streams mix.
// ---------------------------------------------------------------------------
__global__ __launch_bounds__(1024) void kfused(const float* __restrict__ x,
                                               const unsigned short* __restrict__ wpack,
                                               float* __restrict__ out) {
    const int tid = threadIdx.x;
    const int w = tid >> 6, l = tid & 63, lm = l & 15, lk = l >> 4;
    const int tb = (int)blockIdx.x * 16;

    const bf16x8* wbm8 = (const bf16x8*)(wpack + WBM_E);
    const bf16x8* wrb8 = (const bf16x8*)(wpack + WRB_E);
    const bf16x8* bb8  = (const bf16x8*)(wpack + BB_E);

    __shared__ float red[2][16][6][16][4];        // 48 KB, double-buffered
    __shared__ __align__(16) unsigned short mfb[2][8][16][8];   // 4 KB
    __shared__ float mids[4][64];
    __shared__ float lgr[4][4];

    // zero mfb (token slots 4-15 must stay zero forever)
    ((int*)mfb)[tid] = 0;
    ((int*)mfb)[tid + 1024] = 0;

    // ---- one-time register preload: W frags (K-chunk w*256) ----
    bf16x8 wreg[8][5];
#pragma unroll
    for (int s = 0; s < 8; ++s) {
        const int kb8 = w * 32 + s * 4 + lk;
        wreg[s][0] = wbm8[kb8 * 64 +  0 + lm];
        wreg[s][1] = wbm8[kb8 * 64 + 16 + lm];
        wreg[s][2] = wbm8[kb8 * 64 + 32 + lm];
        wreg[s][3] = wbm8[kb8 * 64 + 48 + lm];
        wreg[s][4] = wrb8[kb8 * 16 + lm];
    }
    // ---- one-time register preload: B frags (col-chunk w*256) ----
    const int ob = w * 256;
    bf16x8 breg[16][2];
#pragma unroll
    for (int n = 0; n < 16; ++n) {
        breg[n][0] = bb8[(size_t)lk * 4096 + ob + n * 16 + lm];
        breg[n][1] = bb8[(size_t)(4 + lk) * 4096 + ob + n * 16 + lm];
    }

    for (int g = 0; g < 4; ++g) {
        const int b = g & 1;
        // ---- phase A: mid+router MFMA for 4 tokens (rows lm&3, 4x dup) ----
        f32x4 am0 = {0.f,0.f,0.f,0.f}, am1 = am0, am2 = am0, am3 = am0;
        f32x4 ar0 = am0, ar1 = am0;
        const float* xrow = x + (size_t)(tb + g * 4 + (lm & 3)) * F_IN;
#pragma unroll
        for (int s = 0; s < 8; ++s) {
            const int kc = w * 256 + s * 32 + lk * 8;
            float4 xa = *(const float4*)(xrow + kc);
            float4 xb = *(const float4*)(xrow + kc + 4);
            float f[8] = {xa.x, xa.y, xa.z, xa.w, xb.x, xb.y, xb.z, xb.w};
            i32x4 hi_i, lo_i;
#pragma unroll
            for (int p = 0; p < 4; ++p) {
                float a = f[2*p], bq = f[2*p+1];
                int pk = cvt_pk(a, bq);
                float la = a - __uint_as_float(((unsigned)pk) << 16);
                float lb = bq - __uint_as_float((unsigned)pk & 0xffff0000u);
                hi_i[p] = pk;
                lo_i[p] = cvt_pk(la, lb);
            }
            bf16x8 xhi = __builtin_bit_cast(bf16x8, hi_i);
            bf16x8 xlo = __builtin_bit_cast(bf16x8, lo_i);
            am0 = __builtin_amdgcn_mfma_f32_16x16x32_bf16(xhi, wreg[s][0], am0, 0, 0, 0);
            am1 = __builtin_amdgcn_mfma_f32_16x16x32_bf16(xhi, wreg[s][1], am1, 0, 0, 0);
            am2 = __builtin_amdgcn_mfma_f32_16x16x32_bf16(xhi, wreg[s][2], am2, 0, 0, 0);
            am3 = __builtin_amdgcn_mfma_f32_16x16x32_bf16(xhi, wreg[s][3], am3, 0, 0, 0);
            ar0 = __builtin_amdgcn_mfma_f32_16x16x32_bf16(xhi, wreg[s][4], ar0, 0, 0, 0);
            ar1 = __builtin_amdgcn_mfma_f32_16x16x32_bf16(xlo, wreg[s][4], ar1, 0, 0, 0);
        }
        // all lk groups hold identical values (dup rows); lk==0 writes
        if (lk == 0) {
            *(f32x4*)&red[b][w][0][lm][0] = am0;
            *(f32x4*)&red[b][w][1][lm][0] = am1;
            *(f32x4*)&red[b][w][2][lm][0] = am2;
            *(f32x4*)&red[b][w][3][lm][0] = am3;
            *(f32x4*)&red[b][w][4][lm][0] = ar0;
            *(f32x4*)&red[b][w][5][lm][0] = ar1;
        }
        __syncthreads();

        if (tid < 256) {               // mid reduce: tile 0-3, col c, token t
            const int tile = tid >> 6, c = (tid >> 2) & 15, t = tid & 3;
            float s = 0.f;
#pragma unroll
            for (int ww = 0; ww < 16; ++ww) s += red[b][ww][tile][c][t];
            mids[t][tile * 16 + c] = s;
        } else if (tid < 272) {        // router reduce: (t,e)
            const int j = tid - 256, t = j & 3, e = j >> 2;
            float s = 0.f;
#pragma unroll
            for (int ww = 0; ww < 16; ++ww)
                s += red[b][ww][4][e][t] + red[b][ww][4][4 + e][t]
                   + red[b][ww][5][e][t] + red[b][ww][5][4 + e][t];
            lgr[t][e] = s;
        }
        __syncthreads();

        if (tid < 128) {               // gate (recomputed per thread) + pack
            const int t = tid & 3, k0 = (tid >> 2) * 2;
            float lg[4] = {lgr[t][0], lgr[t][1], lgr[t][2], lgr[t][3]};
            int i1 = 0; float m1 = lg[0];
#pragma unroll
            for (int e = 1; e < 4; ++e)
                if (lg[e] > m1) { m1 = lg[e]; i1 = e; }
            int i2 = -1; float m2 = 0.f;
#pragma unroll
            for (int e = 0; e < 4; ++e)
                if (e != i1 && (i2 < 0 || lg[e] > m2)) { m2 = lg[e]; i2 = e; }
            float ex = __expf(m2 - m1);
            float inv = 1.f / (1.f + ex);
            const int e = k0 >> 4;
            float gv = (e == i1) ? inv * SCALE_F
                     : (e == i2) ? ex * inv * SCALE_F : 0.f;
            int pk = cvt_pk(mids[t][k0] * gv, mids[t][k0 + 1] * gv);
            ((int*)&mfb[b][k0 >> 3][t][0])[(k0 & 7) >> 1] = pk;
        }
        __syncthreads();

        // ---- phase B: swapped-operand MFMA, out cols [ob, ob+256) ----
        const bf16x8 p0 = *(const bf16x8*)&mfb[b][lk][lm][0];
        const bf16x8 p1 = *(const bf16x8*)&mfb[b][4 + lk][lm][0];
#pragma unroll
        for (int n = 0; n < 16; ++n) {
            f32x4 acc = {0.f,0.f,0.f,0.f};
            acc = __builtin_amdgcn_mfma_f32_16x16x32_bf16(breg[n][0], p0, acc, 0, 0, 0);
            acc = __builtin_amdgcn_mfma_f32_16x16x32_bf16(breg[n][1], p1, acc, 0, 0, 0);
            if (lm < 4) {
                float4 r4 = make_float4(acc[0], acc[1], acc[2], acc[3]);
                *(float4*)&out[(size_t)(tb + g * 4 + lm) * O_OUT + ob + n * 16 + lk * 4] = r4;
            }
        }
        // no barrier here: next-gen x-loads overlap these stores;
        // red[b^1] reuse is fenced by the next iteration's first barrier.
        __syncthreads();
    }
}

extern "C" void kernel_launch(void* const* d_in, const int* in_sizes, int n_in,
                              void* d_out, int out_size, void* d_ws, size_t ws_size,
                              hipStream_t stream) {
    const float* x  = (const float*)d_in[0];
    const float* A  = (const float*)d_in[1];
    const float* B  = (const float*)d_in[2];
    const float* Wr = (const float*)d_in[3];
    float* out = (float*)d_out;
    unsigned short* wsu = (unsigned short*)d_ws;

    kprep<<<288, 256, 0, stream>>>(A, Wr, B, wsu);
    kfused<<<256, 1024, 0, stream>>>(x, wsu, out);
}

// Round 7
// 42.151 us; speedup vs baseline: 6.9465x; 6.9465x over previous
//
#include <hip/hip_runtime.h>

#define T_TOKENS 4096
#define F_IN 4096
#define O_OUT 4096
#define SCALE_F 4.0f   // 16 / sqrt(16)

typedef __attribute__((ext_vector_type(8))) short bf16x8;
typedef __attribute__((ext_vector_type(4))) float f32x4;
typedef __attribute__((ext_vector_type(4))) int i32x4;

// ws layout (unsigned short elements)
#define WBM_E 0          // A packed:  [512 kb8][64 col][8]  = 262144
#define WRB_E 262144     // Wr packed: [512 kb8][16 col][8]  =  65536 (c0-3 hi, c4-7 lo, 8-15 zero)
#define BB_E  327680     // B packed:  [8 kb8][4096 o][8]    = 262144
#define PART_F 294912    // float offset (byte 1179648): partial [2][4096][80] fp32 = 2.6 MB

__device__ __forceinline__ unsigned short f2bf(float f) {
    unsigned u = __float_as_uint(f);
    return (unsigned short)((u + 0x7fffu + ((u >> 16) & 1u)) >> 16);
}
__device__ __forceinline__ float bf2f(unsigned short h) {
    return __uint_as_float(((unsigned)h) << 16);
}
__device__ __forceinline__ int cvt_pk(float a, float b) {
    int r;
    asm("v_cvt_pk_bf16_f32 %0, %1, %2" : "=v"(r) : "v"(a), "v"(b));
    return r;   // low16 = bf16(a), high16 = bf16(b)
}

// ---------------------------------------------------------------------------
// kprep: pack A, Wr (hi/lo split), B into MFMA B-operand frags [k>>3][col][k&7].
// ---------------------------------------------------------------------------
__global__ __launch_bounds__(256) void kprep(const float* __restrict__ A,
                                             const float* __restrict__ Wr,
                                             const float* __restrict__ B,
                                             unsigned short* __restrict__ ws) {
    const int f = blockIdx.x * 256 + threadIdx.x;
    if (f < 32768) {                       // A frag: kb8 = f>>6, c = f&63
        const int kb8 = f >> 6, c = f & 63;
        const float* src = A + (size_t)c * F_IN + kb8 * 8;
        float4 a = *(const float4*)src, b = *(const float4*)(src + 4);
        i32x4 v;
        v[0] = cvt_pk(a.x, a.y); v[1] = cvt_pk(a.z, a.w);
        v[2] = cvt_pk(b.x, b.y); v[3] = cvt_pk(b.z, b.w);
        *(i32x4*)(ws + WBM_E + (size_t)f * 8) = v;
    } else if (f < 40960) {                // Wr frag (hi/lo, RNE split)
        const int j = f - 32768;
        const int kb8 = j >> 4, cc = j & 15;
        bf16x8 v = {0,0,0,0,0,0,0,0};
        if (cc < 8) {
            const float* src = Wr + (size_t)(cc & 3) * F_IN + kb8 * 8;
            float4 a = *(const float4*)src, b = *(const float4*)(src + 4);
            float ff[8] = {a.x, a.y, a.z, a.w, b.x, b.y, b.z, b.w};
            if (cc < 4) {
#pragma unroll
                for (int q = 0; q < 8; ++q) v[q] = (short)f2bf(ff[q]);
            } else {
#pragma unroll
                for (int q = 0; q < 8; ++q) {
                    unsigned short h = f2bf(ff[q]);
                    v[q] = (short)f2bf(ff[q] - bf2f(h));
                }
            }
        }
        *(bf16x8*)(ws + WRB_E + (size_t)j * 8) = v;
    } else if (f < 73728) {                // B frag: kb8 = j>>12, o = j&4095
        const int j = f - 40960;
        const int kb8 = j >> 12, o = j & 4095;
        const float* src = B + ((size_t)(kb8 >> 1) * O_OUT + o) * 16 + (kb8 & 1) * 8;
        float4 a = *(const float4*)src, b = *(const float4*)(src + 4);
        i32x4 v;
        v[0] = cvt_pk(a.x, a.y); v[1] = cvt_pk(a.z, a.w);
        v[2] = cvt_pk(b.x, b.y); v[3] = cvt_pk(b.z, b.w);
        *(i32x4*)(ws + BB_E + (size_t)j * 8) = v;
    }
}

// ---------------------------------------------------------------------------
// k1_mid: PURE-READ kernel. Grid 512 = 256 token-groups x 2 K-halves,
// block 512 thr (8 waves, K-chunk 256 each). 6 MFMAs/step, 8 steps.
// LDS 8-way reduce -> fp32 partial [kh][t][80] (2.6 MB). No gating here.
// ---------------------------------------------------------------------------
__global__ __launch_bounds__(512) void k1_mid(const float* __restrict__ x,
                                              const unsigned short* __restrict__ wpack,
                                              float* __restrict__ partial) {
    const int tid = threadIdx.x;
    const int w = tid >> 6, l = tid & 63, lm = l & 15, lk = l >> 4;
    const int tg = (int)blockIdx.x >> 1, kh = (int)blockIdx.x & 1;
    const int tb = tg * 16;
    const int kbase = kh * 2048 + w * 256;

    const bf16x8* wbm8 = (const bf16x8*)(wpack + WBM_E);
    const bf16x8* wrb8 = (const bf16x8*)(wpack + WRB_E);

    f32x4 am0 = {0.f,0.f,0.f,0.f}, am1 = am0, am2 = am0, am3 = am0;
    f32x4 ar0 = am0, ar1 = am0;
    const float* xrow = x + (size_t)(tb + lm) * F_IN;

#pragma unroll
    for (int s = 0; s < 8; ++s) {
        const int kc = kbase + s * 32 + lk * 8;
        float4 xa = *(const float4*)(xrow + kc);
        float4 xb = *(const float4*)(xrow + kc + 4);
        float f[8] = {xa.x, xa.y, xa.z, xa.w, xb.x, xb.y, xb.z, xb.w};
        i32x4 hi_i, lo_i;
#pragma unroll
        for (int p = 0; p < 4; ++p) {
            float a = f[2*p], b = f[2*p+1];
            int pk = cvt_pk(a, b);
            float la = a - __uint_as_float(((unsigned)pk) << 16);
            float lb = b - __uint_as_float((unsigned)pk & 0xffff0000u);
            hi_i[p] = pk;
            lo_i[p] = cvt_pk(la, lb);
        }
        bf16x8 xhi = __builtin_bit_cast(bf16x8, hi_i);
        bf16x8 xlo = __builtin_bit_cast(bf16x8, lo_i);

        const int kb8 = kc >> 3;
        bf16x8 w0 = wbm8[kb8 * 64 +  0 + lm];
        bf16x8 w1 = wbm8[kb8 * 64 + 16 + lm];
        bf16x8 w2 = wbm8[kb8 * 64 + 32 + lm];
        bf16x8 w3 = wbm8[kb8 * 64 + 48 + lm];
        bf16x8 wr = wrb8[kb8 * 16 + lm];
        am0 = __builtin_amdgcn_mfma_f32_16x16x32_bf16(xhi, w0, am0, 0, 0, 0);
        am1 = __builtin_amdgcn_mfma_f32_16x16x32_bf16(xhi, w1, am1, 0, 0, 0);
        am2 = __builtin_amdgcn_mfma_f32_16x16x32_bf16(xhi, w2, am2, 0, 0, 0);
        am3 = __builtin_amdgcn_mfma_f32_16x16x32_bf16(xhi, w3, am3, 0, 0, 0);
        ar0 = __builtin_amdgcn_mfma_f32_16x16x32_bf16(xhi, wr, ar0, 0, 0, 0);
        ar1 = __builtin_amdgcn_mfma_f32_16x16x32_bf16(xlo, wr, ar1, 0, 0, 0);
    }

    __shared__ float red[8][6][64][4];      // 48 KB
    *(f32x4*)&red[w][0][l][0] = am0;
    *(f32x4*)&red[w][1][l][0] = am1;
    *(f32x4*)&red[w][2][l][0] = am2;
    *(f32x4*)&red[w][3][l][0] = am3;
    *(f32x4*)&red[w][4][l][0] = ar0;
    *(f32x4*)&red[w][5][l][0] = ar1;
    __syncthreads();

#pragma unroll
    for (int it = 0; it < 3; ++it) {
        int j = tid + it * 512;              // 0..1535
        int tile = j >> 8, rem = j & 255, rl = rem >> 2, q = rem & 3;
        float s = 0.f;
#pragma unroll
        for (int ww = 0; ww < 8; ++ww) s += red[ww][tile][rl][q];
        int token = ((rl >> 4) << 2) + q, c = rl & 15;
        int col;
        if (tile < 4)      col = tile * 16 + c;
        else if (c < 8)    col = (tile == 4 ? 64 : 72) + c;
        else               col = -1;
        if (col >= 0)
            partial[(size_t)kh * T_TOKENS * 80 + (size_t)(tb + token) * 80 + col] = s;
    }
}

// ---------------------------------------------------------------------------
// k2_out: PURE-WRITE kernel. Grid 1024 = 64 token-tiles x 16 col-tiles,
// block 256 thr. Prologue: reduce partial (2 kh), top-2 softmax gate,
// pack gated mids -> bf16 A-frags in LDS. Then 4 waves x (16 tok x 256 cols)
// expand vs packed B, store 64 MB out.
// ---------------------------------------------------------------------------
__global__ __launch_bounds__(256) void k2_out(const float* __restrict__ partial,
                                              const unsigned short* __restrict__ wpack,
                                              float* __restrict__ out) {
    const int tid = threadIdx.x;
    const int tb = ((int)blockIdx.x >> 4) * 64;
    const int ob = ((int)blockIdx.x & 15) * 256;

    __shared__ float mids[64][64];                    // 16 KB
    __shared__ float lgq[64][4][4];                   // 4 KB  [t][g][e]
    __shared__ float gl[64][4];                       // 1 KB
    __shared__ __align__(16) unsigned short mfr[8][64][8];   // 8 KB

    const f32x4* p4 = (const f32x4*)partial;          // [2][4096][20]
    const int KHS = T_TOKENS * 20;                    // f32x4 stride per kh

    // reduce mids (cols 0..63)
#pragma unroll
    for (int i = 0; i < 4; ++i) {
        int idx = tid + i * 256;                      // 0..1023
        int t = idx >> 4, c4 = idx & 15;
        f32x4 v = p4[(size_t)(tb + t) * 20 + c4] + p4[(size_t)KHS + (tb + t) * 20 + c4];
        *(f32x4*)&mids[t][c4 * 4] = v;
    }
    // reduce logit partials (cols 64..79)
    {
        int t = tid >> 2, g = tid & 3;
        f32x4 v = p4[(size_t)(tb + t) * 20 + 16 + g] + p4[(size_t)KHS + (tb + t) * 20 + 16 + g];
        *(f32x4*)&lgq[t][g][0] = v;
    }
    __syncthreads();

    if (tid < 64) {
        const int t = tid;
        float lg[4];
#pragma unroll
        for (int e = 0; e < 4; ++e)
            lg[e] = lgq[t][0][e] + lgq[t][1][e] + lgq[t][2][e] + lgq[t][3][e];
        int i1 = 0; float m1 = lg[0];
#pragma unroll
        for (int e = 1; e < 4; ++e)
            if (lg[e] > m1) { m1 = lg[e]; i1 = e; }
        int i2 = -1; float m2 = 0.f;
#pragma unroll
        for (int e = 0; e < 4; ++e)
            if (e != i1 && (i2 < 0 || lg[e] > m2)) { m2 = lg[e]; i2 = e; }
        float ex = __expf(m2 - m1);
        float inv = 1.f / (1.f + ex);
#pragma unroll
        for (int e = 0; e < 4; ++e) gl[t][e] = 0.f;
        gl[t][i1] = inv * SCALE_F;
        gl[t][i2] = ex * inv * SCALE_F;
    }
    __syncthreads();

    // pack gated mids -> bf16 A-frags
#pragma unroll
    for (int i = 0; i < 8; ++i) {
        int j = tid + i * 256;                        // 0..2047
        int t = j >> 5, kp = j & 31, k0 = kp * 2;
        float g = gl[t][k0 >> 4];
        int pk = cvt_pk(mids[t][k0] * g, mids[t][k0 + 1] * g);
        *(int*)&mfr[k0 >> 3][t][k0 & 7] = pk;
    }
    __syncthreads();

    // expand: wave w -> tokens [tb + w*16, +16), cols [ob, ob+256)
    const int w = tid >> 6, l = tid & 63, lm = l & 15, lk = l >> 4;
    const bf16x8* bb8 = (const bf16x8*)(wpack + BB_E);
    const bf16x8 p0 = *(const bf16x8*)&mfr[lk][w * 16 + lm][0];
    const bf16x8 p1 = *(const bf16x8*)&mfr[4 + lk][w * 16 + lm][0];

#pragma unroll 4
    for (int n = 0; n < 16; ++n) {
        const int oc = ob + n * 16;
        bf16x8 b0 = bb8[(size_t)lk * 4096 + oc + lm];
        bf16x8 b1 = bb8[(size_t)(4 + lk) * 4096 + oc + lm];
        f32x4 acc = {0.f,0.f,0.f,0.f};
        acc = __builtin_amdgcn_mfma_f32_16x16x32_bf16(p0, b0, acc, 0, 0, 0);
        acc = __builtin_amdgcn_mfma_f32_16x16x32_bf16(p1, b1, acc, 0, 0, 0);
#pragma unroll
        for (int q = 0; q < 4; ++q)
            out[(size_t)(tb + w * 16 + lk * 4 + q) * O_OUT + oc + lm] = acc[q];
    }
}

extern "C" void kernel_launch(void* const* d_in, const int* in_sizes, int n_in,
                              void* d_out, int out_size, void* d_ws, size_t ws_size,
                              hipStream_t stream) {
    const float* x  = (const float*)d_in[0];
    const float* A  = (const float*)d_in[1];
    const float* B  = (const float*)d_in[2];
    const float* Wr = (const float*)d_in[3];
    float* out = (float*)d_out;
    unsigned short* wsu = (unsigned short*)d_ws;
    float* partial = (float*)d_ws + PART_F;

    kprep<<<288, 256, 0, stream>>>(A, Wr, B, wsu);
    k1_mid<<<512, 512, 0, stream>>>(x, wsu, partial);
    k2_out<<<1024, 256, 0, stream>>>(partial, wsu, out);
}

// Round 8
// 39.254 us; speedup vs baseline: 7.4593x; 1.0738x over previous
//
#include <hip/hip_runtime.h>

#define T_TOKENS 4096
#define F_IN 4096
#define O_OUT 4096
#define SCALE_F 4.0f   // 16 / sqrt(16)

typedef __attribute__((ext_vector_type(8))) short bf16x8;
typedef __attribute__((ext_vector_type(4))) float f32x4;
typedef __attribute__((ext_vector_type(4))) int i32x4;

// ws layout (unsigned short elements)
#define WBM_E 0          // A packed:  [512 kb8][64 col][8]  = 262144
#define WRB_E 262144     // Wr packed: [512 kb8][16 col][8]  =  65536 (c0-3 hi, c4-7 lo, 8-15 zero)
#define BB_E  327680     // B packed:  [8 kb8][4096 o][8]    = 262144

__device__ __forceinline__ unsigned short f2bf(float f) {
    unsigned u = __float_as_uint(f);
    return (unsigned short)((u + 0x7fffu + ((u >> 16) & 1u)) >> 16);
}
__device__ __forceinline__ float bf2f(unsigned short h) {
    return __uint_as_float(((unsigned)h) << 16);
}
__device__ __forceinline__ int cvt_pk(float a, float b) {
    int r;
    asm("v_cvt_pk_bf16_f32 %0, %1, %2" : "=v"(r) : "v"(a), "v"(b));
    return r;   // low16 = bf16(a), high16 = bf16(b)
}

// ---------------------------------------------------------------------------
// kprep: pack A, Wr (hi/lo split), B into MFMA B-operand frags [k>>3][col][k&7].
// ---------------------------------------------------------------------------
__global__ __launch_bounds__(256) void kprep(const float* __restrict__ A,
                                             const float* __restrict__ Wr,
                                             const float* __restrict__ B,
                                             unsigned short* __restrict__ ws) {
    const int f = blockIdx.x * 256 + threadIdx.x;
    if (f < 32768) {                       // A frag: kb8 = f>>6, c = f&63
        const int kb8 = f >> 6, c = f & 63;
        const float* src = A + (size_t)c * F_IN + kb8 * 8;
        float4 a = *(const float4*)src, b = *(const float4*)(src + 4);
        i32x4 v;
        v[0] = cvt_pk(a.x, a.y); v[1] = cvt_pk(a.z, a.w);
        v[2] = cvt_pk(b.x, b.y); v[3] = cvt_pk(b.z, b.w);
        *(i32x4*)(ws + WBM_E + (size_t)f * 8) = v;
    } else if (f < 40960) {                // Wr frag (hi/lo, RNE split)
        const int j = f - 32768;
        const int kb8 = j >> 4, cc = j & 15;
        bf16x8 v = {0,0,0,0,0,0,0,0};
        if (cc < 8) {
            const float* src = Wr + (size_t)(cc & 3) * F_IN + kb8 * 8;
            float4 a = *(const float4*)src, b = *(const float4*)(src + 4);
            float ff[8] = {a.x, a.y, a.z, a.w, b.x, b.y, b.z, b.w};
            if (cc < 4) {
#pragma unroll
                for (int q = 0; q < 8; ++q) v[q] = (short)f2bf(ff[q]);
            } else {
#pragma unroll
                for (int q = 0; q < 8; ++q) {
                    unsigned short h = f2bf(ff[q]);
                    v[q] = (short)f2bf(ff[q] - bf2f(h));
                }
            }
        }
        *(bf16x8*)(ws + WRB_E + (size_t)j * 8) = v;
    } else if (f < 73728) {                // B frag: kb8 = j>>12, o = j&4095
        const int j = f - 40960;
        const int kb8 = j >> 12, o = j & 4095;
        const float* src = B + ((size_t)(kb8 >> 1) * O_OUT + o) * 16 + (kb8 & 1) * 8;
        float4 a = *(const float4*)src, b = *(const float4*)(src + 4);
        i32x4 v;
        v[0] = cvt_pk(a.x, a.y); v[1] = cvt_pk(a.z, a.w);
        v[2] = cvt_pk(b.x, b.y); v[3] = cvt_pk(b.z, b.w);
        *(i32x4*)(ws + BB_E + (size_t)j * 8) = v;
    }
}

// one phase-1 MFMA step: hi/lo split of 8 x-values + 6 MFMAs
__device__ __forceinline__ void ph1_step(float4 xa, float4 xb, int kb8, int lm,
                                         const bf16x8* __restrict__ wbm8,
                                         const bf16x8* __restrict__ wrb8,
                                         f32x4& am0, f32x4& am1, f32x4& am2,
                                         f32x4& am3, f32x4& ar0, f32x4& ar1) {
    float f[8] = {xa.x, xa.y, xa.z, xa.w, xb.x, xb.y, xb.z, xb.w};
    i32x4 hi_i, lo_i;
#pragma unroll
    for (int p = 0; p < 4; ++p) {
        float a = f[2*p], b = f[2*p+1];
        int pk = cvt_pk(a, b);
        float la = a - __uint_as_float(((unsigned)pk) << 16);
        float lb = b - __uint_as_float((unsigned)pk & 0xffff0000u);
        hi_i[p] = pk;
        lo_i[p] = cvt_pk(la, lb);
    }
    bf16x8 xhi = __builtin_bit_cast(bf16x8, hi_i);
    bf16x8 xlo = __builtin_bit_cast(bf16x8, lo_i);
    bf16x8 w0 = wbm8[kb8 * 64 +  0 + lm];
    bf16x8 w1 = wbm8[kb8 * 64 + 16 + lm];
    bf16x8 w2 = wbm8[kb8 * 64 + 32 + lm];
    bf16x8 w3 = wbm8[kb8 * 64 + 48 + lm];
    bf16x8 wr = wrb8[kb8 * 16 + lm];
    am0 = __builtin_amdgcn_mfma_f32_16x16x32_bf16(xhi, w0, am0, 0, 0, 0);
    am1 = __builtin_amdgcn_mfma_f32_16x16x32_bf16(xhi, w1, am1, 0, 0, 0);
    am2 = __builtin_amdgcn_mfma_f32_16x16x32_bf16(xhi, w2, am2, 0, 0, 0);
    am3 = __builtin_amdgcn_mfma_f32_16x16x32_bf16(xhi, w3, am3, 0, 0, 0);
    ar0 = __builtin_amdgcn_mfma_f32_16x16x32_bf16(xhi, wr, ar0, 0, 0, 0);
    ar1 = __builtin_amdgcn_mfma_f32_16x16x32_bf16(xlo, wr, ar1, 0, 0, 0);
}

// ---------------------------------------------------------------------------
// kfused: grid 256, 512 thr (8 waves x K-chunk 512). Phase 1 with whole-chunk
// x register prefetch (two 16-load batches -> latency exposed ~once/wave).
// Reduce + gate + pack as before. Phase 2 swapped-operand (float4 stores).
// ---------------------------------------------------------------------------
__global__ __launch_bounds__(512) void kfused(const float* __restrict__ x,
                                              const unsigned short* __restrict__ wpack,
                                              float* __restrict__ out) {
    const int tid = threadIdx.x;
    const int w = tid >> 6, l = tid & 63, lm = l & 15, lk = l >> 4;
    const int tb = (int)blockIdx.x * 16;
    const int kbase = w * 512;

    const bf16x8* wbm8 = (const bf16x8*)(wpack + WBM_E);
    const bf16x8* wrb8 = (const bf16x8*)(wpack + WRB_E);
    const bf16x8* bb8  = (const bf16x8*)(wpack + BB_E);

    f32x4 am0 = {0.f,0.f,0.f,0.f}, am1 = am0, am2 = am0, am3 = am0;
    f32x4 ar0 = am0, ar1 = am0;
    const float* xrow = x + (size_t)(tb + lm) * F_IN + kbase + lk * 8;
    const int kb80 = (kbase >> 3) + lk;    // kb8 of step 0

    // ---- prefetch entire K-chunk of x into registers (2 x 16 loads) ----
    float4 xA[16], xB[16];
#pragma unroll
    for (int j = 0; j < 8; ++j) {
        xA[2*j]   = *(const float4*)(xrow + j * 32);
        xA[2*j+1] = *(const float4*)(xrow + j * 32 + 4);
    }
#pragma unroll
    for (int j = 0; j < 8; ++j) {
        xB[2*j]   = *(const float4*)(xrow + 256 + j * 32);
        xB[2*j+1] = *(const float4*)(xrow + 256 + j * 32 + 4);
    }
#pragma unroll
    for (int j = 0; j < 8; ++j)
        ph1_step(xA[2*j], xA[2*j+1], kb80 + j * 4, lm, wbm8, wrb8,
                 am0, am1, am2, am3, ar0, ar1);
#pragma unroll
    for (int j = 0; j < 8; ++j)
        ph1_step(xB[2*j], xB[2*j+1], kb80 + 32 + j * 4, lm, wbm8, wrb8,
                 am0, am1, am2, am3, ar0, ar1);

    __shared__ float red[8][6][64][4];      // 48 KB
    __shared__ float mids[16][68];
    __shared__ float lgp[2][16][16];
    __shared__ float gl[16][4];
    __shared__ __align__(16) unsigned short mfr[8][16][8];

    *(f32x4*)&red[w][0][l][0] = am0;
    *(f32x4*)&red[w][1][l][0] = am1;
    *(f32x4*)&red[w][2][l][0] = am2;
    *(f32x4*)&red[w][3][l][0] = am3;
    *(f32x4*)&red[w][4][l][0] = ar0;
    *(f32x4*)&red[w][5][l][0] = ar1;
    __syncthreads();

#pragma unroll
    for (int it = 0; it < 3; ++it) {
        int j = tid + it * 512;              // 0..1535
        int tile = j >> 8, rem = j & 255, rl = rem >> 2, q = rem & 3;
        float s = 0.f;
#pragma unroll
        for (int ww = 0; ww < 8; ++ww) s += red[ww][tile][rl][q];
        int token = ((rl >> 4) << 2) + q, c = rl & 15;
        if (tile < 4) mids[token][tile * 16 + c] = s;
        else          lgp[tile - 4][token][c] = s;
    }
    __syncthreads();

    if (tid < 16) {
        float lg[4];
#pragma unroll
        for (int e = 0; e < 4; ++e)
            lg[e] = lgp[0][tid][e] + lgp[0][tid][4 + e]
                  + lgp[1][tid][e] + lgp[1][tid][4 + e];
        int i1 = 0; float m1 = lg[0];
#pragma unroll
        for (int e = 1; e < 4; ++e)
            if (lg[e] > m1) { m1 = lg[e]; i1 = e; }
        int i2 = -1; float m2 = 0.f;
#pragma unroll
        for (int e = 0; e < 4; ++e)
            if (e != i1 && (i2 < 0 || lg[e] > m2)) { m2 = lg[e]; i2 = e; }
        float ex = __expf(m2 - m1);
        float inv = 1.f / (1.f + ex);
#pragma unroll
        for (int e = 0; e < 4; ++e) gl[tid][e] = 0.f;
        gl[tid][i1] = inv * SCALE_F;
        gl[tid][i2] = ex * inv * SCALE_F;
    }
    __syncthreads();

    {   // pack gated mids -> bf16 B-operand frags (512 threads, 512 pairs)
        int t = tid & 15, kp = tid >> 4;      // kp 0..31
        int k0 = kp * 2;
        float g = gl[t][k0 >> 4];             // k0,k0+1 never straddle an expert
        int pk = cvt_pk(mids[t][k0] * g, mids[t][k0 + 1] * g);
        *(int*)&mfr[k0 >> 3][t][k0 & 7] = pk;
    }
    __syncthreads();

    // ---- Phase 2 (swapped operands): wave w -> out[tb..tb+15][w*512..+512) ----
    // A-operand = B-frag (rows = out cols), B-operand = midw frag (cols = tokens)
    // C: col(lane&15)=token, row((lane>>4)*4+q)=out col -> float4 store per lane.
    const int ob = w * 512;
    const bf16x8 p0 = *(const bf16x8*)&mfr[lk][lm][0];
    const bf16x8 p1 = *(const bf16x8*)&mfr[4 + lk][lm][0];

#pragma unroll 4
    for (int n = 0; n < 32; ++n) {
        const int oc = ob + n * 16;
        bf16x8 b0 = bb8[(size_t)lk * 4096 + oc + lm];
        bf16x8 b1 = bb8[(size_t)(4 + lk) * 4096 + oc + lm];
        f32x4 acc = {0.f,0.f,0.f,0.f};
        acc = __builtin_amdgcn_mfma_f32_16x16x32_bf16(b0, p0, acc, 0, 0, 0);
        acc = __builtin_amdgcn_mfma_f32_16x16x32_bf16(b1, p1, acc, 0, 0, 0);
        float4 r4 = make_float4(acc[0], acc[1], acc[2], acc[3]);
        *(float4*)&out[(size_t)(tb + lm) * O_OUT + oc + lk * 4] = r4;
    }
}

extern "C" void kernel_launch(void* const* d_in, const int* in_sizes, int n_in,
                              void* d_out, int out_size, void* d_ws, size_t ws_size,
                              hipStream_t stream) {
    const float* x  = (const float*)d_in[0];
    const float* A  = (const float*)d_in[1];
    const float* B  = (const float*)d_in[2];
    const float* Wr = (const float*)d_in[3];
    float* out = (float*)d_out;
    unsigned short* wsu = (unsigned short*)d_ws;

    kprep<<<288, 256, 0, stream>>>(A, Wr, B, wsu);
    kfused<<<256, 512, 0, stream>>>(x, wsu, out);
}

// Round 9
// 38.004 us; speedup vs baseline: 7.7046x; 1.0329x over previous
//
#include <hip/hip_runtime.h>

#define T_TOKENS 4096
#define F_IN 4096
#define O_OUT 4096
#define SCALE_F 4.0f   // 16 / sqrt(16)

typedef __attribute__((ext_vector_type(8))) short bf16x8;
typedef __attribute__((ext_vector_type(4))) float f32x4;
typedef __attribute__((ext_vector_type(4))) int i32x4;

// ws layout (unsigned short elements)
#define WBM_E 0          // A packed:  [512 kb8][64 col][8]  = 262144
#define WRB_E 262144     // Wr packed: [512 kb8][16 col][8]  =  65536 (c0-3 hi, c4-7 lo, 8-15 zero)
#define BB_E  327680     // B packed:  [8 kb8][4096 o][8]    = 262144

__device__ __forceinline__ unsigned short f2bf(float f) {
    unsigned u = __float_as_uint(f);
    return (unsigned short)((u + 0x7fffu + ((u >> 16) & 1u)) >> 16);
}
__device__ __forceinline__ float bf2f(unsigned short h) {
    return __uint_as_float(((unsigned)h) << 16);
}
__device__ __forceinline__ int cvt_pk(float a, float b) {
    int r;
    asm("v_cvt_pk_bf16_f32 %0, %1, %2" : "=v"(r) : "v"(a), "v"(b));
    return r;   // low16 = bf16(a), high16 = bf16(b)
}

// ---------------------------------------------------------------------------
// kprep: pack A, Wr (hi/lo split), B into MFMA B-operand frags [k>>3][col][k&7].
// One 8-elem frag per thread: 32768 (A) + 8192 (Wr) + 32768 (B) = 73728.
// ---------------------------------------------------------------------------
__global__ __launch_bounds__(256) void kprep(const float* __restrict__ A,
                                             const float* __restrict__ Wr,
                                             const float* __restrict__ B,
                                             unsigned short* __restrict__ ws) {
    const int f = blockIdx.x * 256 + threadIdx.x;
    if (f < 32768) {                       // A frag: kb8 = f>>6, c = f&63
        const int kb8 = f >> 6, c = f & 63;
        const float* src = A + (size_t)c * F_IN + kb8 * 8;
        float4 a = *(const float4*)src, b = *(const float4*)(src + 4);
        i32x4 v;
        v[0] = cvt_pk(a.x, a.y); v[1] = cvt_pk(a.z, a.w);
        v[2] = cvt_pk(b.x, b.y); v[3] = cvt_pk(b.z, b.w);
        *(i32x4*)(ws + WBM_E + (size_t)f * 8) = v;
    } else if (f < 40960) {                // Wr frag (hi/lo, RNE split)
        const int j = f - 32768;
        const int kb8 = j >> 4, cc = j & 15;
        bf16x8 v = {0,0,0,0,0,0,0,0};
        if (cc < 8) {
            const float* src = Wr + (size_t)(cc & 3) * F_IN + kb8 * 8;
            float4 a = *(const float4*)src, b = *(const float4*)(src + 4);
            float ff[8] = {a.x, a.y, a.z, a.w, b.x, b.y, b.z, b.w};
            if (cc < 4) {
#pragma unroll
                for (int q = 0; q < 8; ++q) v[q] = (short)f2bf(ff[q]);
            } else {
#pragma unroll
                for (int q = 0; q < 8; ++q) {
                    unsigned short h = f2bf(ff[q]);
                    v[q] = (short)f2bf(ff[q] - bf2f(h));
                }
            }
        }
        *(bf16x8*)(ws + WRB_E + (size_t)j * 8) = v;
    } else if (f < 73728) {                // B frag: kb8 = j>>12, o = j&4095
        const int j = f - 40960;
        const int kb8 = j >> 12, o = j & 4095;
        const float* src = B + ((size_t)(kb8 >> 1) * O_OUT + o) * 16 + (kb8 & 1) * 8;
        float4 a = *(const float4*)src, b = *(const float4*)(src + 4);
        i32x4 v;
        v[0] = cvt_pk(a.x, a.y); v[1] = cvt_pk(a.z, a.w);
        v[2] = cvt_pk(b.x, b.y); v[3] = cvt_pk(b.z, b.w);
        *(i32x4*)(ws + BB_E + (size_t)j * 8) = v;
    }
}

// ---------------------------------------------------------------------------
// kfused: one block = 16 tokens, 512 threads (8 waves x K-chunk 512).
// Phase 1: x @ [A;Wr_hi;Wr_lo] via MFMA (6/step, no duplication).
// LDS 8-way reduce -> fp32 top-2 softmax -> gate*SCALE -> midw bf16 frags in LDS.
// Phase 2: wave w computes out[tb..tb+15][w*512..+512) = midw @ Bcat (K=64).
// Grid 256 (1 block/CU).
// ---------------------------------------------------------------------------
__global__ __launch_bounds__(512) void kfused(const float* __restrict__ x,
                                              const unsigned short* __restrict__ wpack,
                                              float* __restrict__ out) {
    const int tid = threadIdx.x;
    const int w = tid >> 6, l = tid & 63, lm = l & 15, lk = l >> 4;
    const int tb = (int)blockIdx.x * 16;
    const int kbase = w * 512;

    const bf16x8* wbm8 = (const bf16x8*)(wpack + WBM_E);
    const bf16x8* wrb8 = (const bf16x8*)(wpack + WRB_E);
    const bf16x8* bb8  = (const bf16x8*)(wpack + BB_E);

    f32x4 am0 = {0.f,0.f,0.f,0.f}, am1 = am0, am2 = am0, am3 = am0;
    f32x4 ar0 = am0, ar1 = am0;
    const float* xrow = x + (size_t)(tb + lm) * F_IN;

#pragma unroll 4
    for (int s = 0; s < 16; ++s) {
        const int kc = kbase + s * 32 + lk * 8;
        float4 xa = *(const float4*)(xrow + kc);
        float4 xb = *(const float4*)(xrow + kc + 4);
        float f[8] = {xa.x, xa.y, xa.z, xa.w, xb.x, xb.y, xb.z, xb.w};
        i32x4 hi_i, lo_i;
#pragma unroll
        for (int p = 0; p < 4; ++p) {
            float a = f[2*p], b = f[2*p+1];
            int pk = cvt_pk(a, b);
            float la = a - __uint_as_float(((unsigned)pk) << 16);
            float lb = b - __uint_as_float((unsigned)pk & 0xffff0000u);
            hi_i[p] = pk;
            lo_i[p] = cvt_pk(la, lb);
        }
        bf16x8 xhi = __builtin_bit_cast(bf16x8, hi_i);
        bf16x8 xlo = __builtin_bit_cast(bf16x8, lo_i);

        const int kb8 = kc >> 3;
        bf16x8 w0 = wbm8[kb8 * 64 +  0 + lm];
        bf16x8 w1 = wbm8[kb8 * 64 + 16 + lm];
        bf16x8 w2 = wbm8[kb8 * 64 + 32 + lm];
        bf16x8 w3 = wbm8[kb8 * 64 + 48 + lm];
        bf16x8 wr = wrb8[kb8 * 16 + lm];
        am0 = __builtin_amdgcn_mfma_f32_16x16x32_bf16(xhi, w0, am0, 0, 0, 0);
        am1 = __builtin_amdgcn_mfma_f32_16x16x32_bf16(xhi, w1, am1, 0, 0, 0);
        am2 = __builtin_amdgcn_mfma_f32_16x16x32_bf16(xhi, w2, am2, 0, 0, 0);
        am3 = __builtin_amdgcn_mfma_f32_16x16x32_bf16(xhi, w3, am3, 0, 0, 0);
        ar0 = __builtin_amdgcn_mfma_f32_16x16x32_bf16(xhi, wr, ar0, 0, 0, 0);
        ar1 = __builtin_amdgcn_mfma_f32_16x16x32_bf16(xlo, wr, ar1, 0, 0, 0);
    }

    __shared__ float red[8][6][64][4];      // 48 KB
    __shared__ float mids[16][68];
    __shared__ float lgp[2][16][16];
    __shared__ float gl[16][4];
    __shared__ __align__(16) unsigned short mfr[8 * 16 * 8];   // [kb8][token][ki]

    *(f32x4*)&red[w][0][l][0] = am0;
    *(f32x4*)&red[w][1][l][0] = am1;
    *(f32x4*)&red[w][2][l][0] = am2;
    *(f32x4*)&red[w][3][l][0] = am3;
    *(f32x4*)&red[w][4][l][0] = ar0;
    *(f32x4*)&red[w][5][l][0] = ar1;
    __syncthreads();

#pragma unroll
    for (int it = 0; it < 3; ++it) {
        int j = tid + it * 512;
        int tile = j >> 8, rem = j & 255, rl = rem >> 2, q = rem & 3;
        float s = 0.f;
#pragma unroll
        for (int ww = 0; ww < 8; ++ww) s += red[ww][tile][rl][q];
        int token = ((rl >> 4) << 2) + q, c = rl & 15;
        if (tile < 4) mids[token][tile * 16 + c] = s;
        else          lgp[tile - 4][token][c] = s;
    }
    __syncthreads();

    if (tid < 16) {
        float lg[4];
#pragma unroll
        for (int e = 0; e < 4; ++e)
            lg[e] = lgp[0][tid][e] + lgp[0][tid][4 + e]
                  + lgp[1][tid][e] + lgp[1][tid][4 + e];
        int i1 = 0; float m1 = lg[0];
#pragma unroll
        for (int e = 1; e < 4; ++e)
            if (lg[e] > m1) { m1 = lg[e]; i1 = e; }
        int i2 = -1; float m2 = 0.f;
#pragma unroll
        for (int e = 0; e < 4; ++e)
            if (e != i1 && (i2 < 0 || lg[e] > m2)) { m2 = lg[e]; i2 = e; }
        float ex = __expf(m2 - m1);
        float inv = 1.f / (1.f + ex);
#pragma unroll
        for (int e = 0; e < 4; ++e) gl[tid][e] = 0.f;
        gl[tid][i1] = inv * SCALE_F;
        gl[tid][i2] = ex * inv * SCALE_F;
    }
    __syncthreads();

    {   // pack gated mids -> bf16 frags: thread handles token t, k = 2*kp, 2*kp+1
        int t = tid & 15, kp = tid >> 4;      // kp 0..31
        int k0 = kp * 2;
        float g = gl[t][k0 >> 4];             // k0,k0+1 never straddle an expert
        int pk = cvt_pk(mids[t][k0] * g, mids[t][k0 + 1] * g);
        *(int*)&mfr[((k0 >> 3) * 16 + t) * 8 + (k0 & 7)] = pk;
    }
    __syncthreads();

    // ---- Phase 2: out tile [16 tokens][512 cols] per wave ----
    const int ob = w * 512;
    const bf16x8* mf8 = (const bf16x8*)mfr;   // frag index kb8*16 + token
    bf16x8 ma0 = mf8[(0 + lk) * 16 + lm];
    bf16x8 ma1 = mf8[(4 + lk) * 16 + lm];

#pragma unroll 4
    for (int n = 0; n < 32; ++n) {
        const int oc = ob + n * 16;
        bf16x8 b0 = bb8[(size_t)lk * 4096 + oc + lm];
        bf16x8 b1 = bb8[(size_t)(4 + lk) * 4096 + oc + lm];
        f32x4 acc = {0.f,0.f,0.f,0.f};
        acc = __builtin_amdgcn_mfma_f32_16x16x32_bf16(ma0, b0, acc, 0, 0, 0);
        acc = __builtin_amdgcn_mfma_f32_16x16x32_bf16(ma1, b1, acc, 0, 0, 0);
#pragma unroll
        for (int q = 0; q < 4; ++q)
            out[(size_t)(tb + lk * 4 + q) * O_OUT + oc + lm] = acc[q];
    }
}

extern "C" void kernel_launch(void* const* d_in, const int* in_sizes, int n_in,
                              void* d_out, int out_size, void* d_ws, size_t ws_size,
                              hipStream_t stream) {
    const float* x  = (const float*)d_in[0];
    const float* A  = (const float*)d_in[1];
    const float* B  = (const float*)d_in[2];
    const float* Wr = (const float*)d_in[3];
    float* out = (float*)d_out;
    unsigned short* wsu = (unsigned short*)d_ws;

    kprep<<<288, 256, 0, stream>>>(A, Wr, B, wsu);
    kfused<<<256, 512, 0, stream>>>(x, wsu, out);
}